// Round 7
// baseline (3249.915 us; speedup 1.0000x reference)
//
#include <hip/hip_runtime.h>

// GIN: 5 layers, DIM=10. Identity: (x+agg)@W1 = x@W1 + segsum((x@W1)[src]).
// R14: R13 hot phase (converged at the random-gather pattern ceiling,
// ~3.5 TB/s across 3 structurally different kernels) + direct CSR build via
// GLOBAL atomics, replacing the bucketed build's 4x 16M-lane LDS-atomic
// rounds (~3.3 cy/lane-op each, R8-measured => ~350us serialized) and the
// 128MB pairs round-trip. Global atomics on DISTINCT addresses parallelize
// across L2 channels (unlike LDS lane-serialization).
//  - R11/R12: launch_bounds(256,8) => hipcc caps VGPR at 32 and spills;
//    (256,4) caps at 64 => no spill, HW still schedules 8 waves/SIMD region.

__device__ __forceinline__ unsigned short f2bf(float f) {
    unsigned b = __float_as_uint(f);
    b += 0x7fffu + ((b >> 16) & 1u);   // round-to-nearest-even
    return (unsigned short)(b >> 16);
}
__device__ __forceinline__ float bflo(unsigned u) { return __uint_as_float(u << 16); }
__device__ __forceinline__ float bfhi(unsigned u) { return __uint_as_float(u & 0xffff0000u); }

// ---------------- Layer-1: y = h @ W1_1 (bf16 rows, 8 uints/row) ----------------
__global__ void k1_hw1_bf16(const float* __restrict__ h, const float* __restrict__ W1,
                            unsigned* __restrict__ y, int N) {
    __shared__ float sW[640];
    for (int i = threadIdx.x; i < 640; i += blockDim.x) sW[i] = W1[i];
    __syncthreads();
    int n = blockIdx.x * blockDim.x + threadIdx.x;
    if (n >= N) return;
    const float* hr = h + (size_t)n * 64;
    float acc[10];
#pragma unroll
    for (int j = 0; j < 10; j++) acc[j] = 0.f;
#pragma unroll 4
    for (int k = 0; k < 64; k += 4) {
        float4 hv = *(const float4*)(hr + k);
#pragma unroll
        for (int j = 0; j < 10; j++) {
            acc[j] += hv.x * sW[(k + 0) * 10 + j];
            acc[j] += hv.y * sW[(k + 1) * 10 + j];
            acc[j] += hv.z * sW[(k + 2) * 10 + j];
            acc[j] += hv.w * sW[(k + 3) * 10 + j];
        }
    }
    unsigned r0 = (unsigned)f2bf(acc[0]) | ((unsigned)f2bf(acc[1]) << 16);
    unsigned r1 = (unsigned)f2bf(acc[2]) | ((unsigned)f2bf(acc[3]) << 16);
    unsigned r2 = (unsigned)f2bf(acc[4]) | ((unsigned)f2bf(acc[5]) << 16);
    unsigned r3 = (unsigned)f2bf(acc[6]) | ((unsigned)f2bf(acc[7]) << 16);
    unsigned r4 = (unsigned)f2bf(acc[8]) | ((unsigned)f2bf(acc[9]) << 16);
    unsigned* yr = y + (size_t)n * 8;
    *(uint4*)yr = make_uint4(r0, r1, r2, r3);
    yr[4] = r4;
}

// f32 variant for the fallback path (16-float rows)
__global__ void k1_hw1_f32(const float* __restrict__ h, const float* __restrict__ W1,
                           float* __restrict__ y, int N) {
    __shared__ float sW[640];
    for (int i = threadIdx.x; i < 640; i += blockDim.x) sW[i] = W1[i];
    __syncthreads();
    int n = blockIdx.x * blockDim.x + threadIdx.x;
    if (n >= N) return;
    const float* hr = h + (size_t)n * 64;
    float acc[10];
#pragma unroll
    for (int j = 0; j < 10; j++) acc[j] = 0.f;
#pragma unroll 4
    for (int k = 0; k < 64; k += 4) {
        float4 hv = *(const float4*)(hr + k);
#pragma unroll
        for (int j = 0; j < 10; j++) {
            acc[j] += hv.x * sW[(k + 0) * 10 + j];
            acc[j] += hv.y * sW[(k + 1) * 10 + j];
            acc[j] += hv.z * sW[(k + 2) * 10 + j];
            acc[j] += hv.w * sW[(k + 3) * 10 + j];
        }
    }
    float* yr = y + (size_t)n * 16;
#pragma unroll
    for (int j = 0; j < 10; j++) yr[j] = acc[j];
}

// =================== CSR build v3: global-atomic count -> scan -> scatter ===================
__global__ __launch_bounds__(256) void k_histN(
        const int* __restrict__ dst, unsigned* __restrict__ cnt, int E) {
    int stride = gridDim.x * blockDim.x;
    for (int e = blockIdx.x * blockDim.x + threadIdx.x; e < E; e += stride)
        atomicAdd(&cnt[(unsigned)dst[e]], 1u);
}

// scan phase A: per-block (8192 elems) total
__global__ __launch_bounds__(1024) void k_scanA(
        const unsigned* __restrict__ cnt, unsigned* __restrict__ bsum, int N) {
    __shared__ unsigned s[1024];
    int t = threadIdx.x;
    size_t base = (size_t)blockIdx.x * 8192 + (size_t)t * 8;
    unsigned sum = 0;
#pragma unroll
    for (int k = 0; k < 8; k++) {
        size_t i = base + k;
        if (i < (size_t)N) sum += cnt[i];
    }
    s[t] = sum;
    __syncthreads();
    for (int off = 512; off > 0; off >>= 1) {
        if (t < off) s[t] += s[t + off];
        __syncthreads();
    }
    if (t == 0) bsum[blockIdx.x] = s[0];
}

// scan phase B: exclusive scan of block sums (nb <= 1024)
__global__ __launch_bounds__(1024) void k_scanB(unsigned* __restrict__ bsum, int nb) {
    __shared__ unsigned s[1024];
    int t = threadIdx.x;
    unsigned v = (t < nb) ? bsum[t] : 0u;
    s[t] = v;
    __syncthreads();
    for (int off = 1; off < 1024; off <<= 1) {
        unsigned u = (t >= off) ? s[t - off] : 0u;
        __syncthreads();
        s[t] += u;
        __syncthreads();
    }
    if (t < nb) bsum[t] = s[t] - v;   // exclusive
}

// scan phase C: full exclusive scan -> row_start + cursor copy
__global__ __launch_bounds__(1024) void k_scanC(
        const unsigned* __restrict__ cnt, const unsigned* __restrict__ bsum,
        unsigned* __restrict__ row_start, unsigned* __restrict__ cur, int N, int E) {
    __shared__ unsigned s[1024];
    int t = threadIdx.x;
    size_t base = (size_t)blockIdx.x * 8192 + (size_t)t * 8;
    unsigned loc[8];
    unsigned sum = 0;
#pragma unroll
    for (int k = 0; k < 8; k++) {
        size_t i = base + k;
        unsigned c = (i < (size_t)N) ? cnt[i] : 0u;
        loc[k] = sum;
        sum += c;
    }
    s[t] = sum;
    __syncthreads();
    for (int off = 1; off < 1024; off <<= 1) {
        unsigned u = (t >= off) ? s[t - off] : 0u;
        __syncthreads();
        s[t] += u;
        __syncthreads();
    }
    unsigned texcl = s[t] - sum + bsum[blockIdx.x];
#pragma unroll
    for (int k = 0; k < 8; k++) {
        size_t i = base + k;
        if (i < (size_t)N) {
            unsigned v = texcl + loc[k];
            row_start[i] = v;
            cur[i] = v;
        }
    }
    if (blockIdx.x == 0 && t == 0) row_start[N] = (unsigned)E;
}

__global__ __launch_bounds__(256) void k_scatterN(
        const int* __restrict__ src, const int* __restrict__ dst,
        unsigned* __restrict__ cur, unsigned* __restrict__ edges, int E) {
    int stride = gridDim.x * blockDim.x;
    for (int e = blockIdx.x * blockDim.x + threadIdx.x; e < E; e += stride) {
        unsigned pos = atomicAdd(&cur[(unsigned)dst[e]], 1u);
        edges[pos] = (unsigned)src[e];
    }
}

// =================== hot phase: quad-per-node fused layer (bf16 rows) ===================
// 4 lanes per node, stride-4 single-row loop with next-edge-index prefetch,
// 20 shfl_xor combine, redundant MLP in all 4 lanes, q==0 writes y_next.
// launch_bounds(256,4): hipcc caps VGPR at 64 -> no spill (R11/R12 lesson).
__global__ __launch_bounds__(256, 4) void k_layerQ(
        const unsigned* __restrict__ yin, unsigned* __restrict__ yout,
        const unsigned* __restrict__ row_start, const unsigned* __restrict__ edges,
        const float* __restrict__ b1, const float* __restrict__ W2,
        const float* __restrict__ b2, const float* __restrict__ l,
        const float* __restrict__ W1n,
        const int* __restrict__ node_graph, float* __restrict__ gacc,
        int N, int last) {
    __shared__ float sW2[100], sW1[100], sb1[10], sb2[10], sl[10];
    int t = threadIdx.x;
    if (t < 100) sW2[t] = W2[t];
    if (!last && t >= 128 && t < 228) sW1[t - 128] = W1n[t - 128];
    if (t < 10) { sb1[t] = b1[t]; sb2[t] = b2[t]; sl[t] = l[t]; }
    __syncthreads();
    int q = t & 3;
    int n = blockIdx.x * 64 + (t >> 2);
    bool valid = n < N;
    int nc = valid ? n : (N - 1);

    float acc[10];
#pragma unroll
    for (int j = 0; j < 10; j++) acc[j] = 0.f;

    unsigned beg = 0, end = 0;
    if (valid) { beg = row_start[n]; end = row_start[n + 1]; }
    unsigned e = beg + (unsigned)q;
    bool have = e < end;
    unsigned sNext = 0;
    if (have) sNext = edges[e];
    while (have) {
        unsigned sCur = sNext;
        unsigned en = e + 4;
        bool hn = en < end;
        if (hn) sNext = edges[en];           // prefetch next edge index
        const unsigned* p = yin + (size_t)sCur * 8;
        uint4 a0 = *(const uint4*)p;
        unsigned b0 = p[4];
        acc[0] += bflo(a0.x); acc[1] += bfhi(a0.x);
        acc[2] += bflo(a0.y); acc[3] += bfhi(a0.y);
        acc[4] += bflo(a0.z); acc[5] += bfhi(a0.z);
        acc[6] += bflo(a0.w); acc[7] += bfhi(a0.w);
        acc[8] += bflo(b0);   acc[9] += bfhi(b0);
        e = en; have = hn;
    }

#pragma unroll
    for (int j = 0; j < 10; j++) acc[j] += __shfl_xor(acc[j], 1);
#pragma unroll
    for (int j = 0; j < 10; j++) acc[j] += __shfl_xor(acc[j], 2);

    const unsigned* yr = yin + (size_t)nc * 8;
    uint4 qa = *(const uint4*)yr;
    unsigned q4 = yr[4];
    acc[0] += bflo(qa.x); acc[1] += bfhi(qa.x);
    acc[2] += bflo(qa.y); acc[3] += bfhi(qa.y);
    acc[4] += bflo(qa.z); acc[5] += bfhi(qa.z);
    acc[6] += bflo(qa.w); acc[7] += bfhi(qa.w);
    acc[8] += bflo(q4);   acc[9] += bfhi(q4);

    float z[10], x[10];
#pragma unroll
    for (int j = 0; j < 10; j++) {
        float v = acc[j] + sb1[j];
        z[j] = v > 0.f ? v : 0.f;
    }
#pragma unroll
    for (int j = 0; j < 10; j++) {
        float v = sb2[j];
#pragma unroll
        for (int k = 0; k < 10; k++) v += z[k] * sW2[k * 10 + j];
        x[j] = v > 0.f ? v : 0.f;
    }
    float p = 0.f;
#pragma unroll
    for (int j = 0; j < 10; j++) p += x[j] * sl[j];
    if (!valid) p = 0.f;
    int g = node_graph[nc];

    int g0 = __shfl(g, 0);
    if (__all(g == g0)) {
        // every node's p appears in 4 lanes -> wave sum is 4x the true sum
#pragma unroll
        for (int off = 32; off > 0; off >>= 1) p += __shfl_down(p, off);
        if ((t & 63) == 0) unsafeAtomicAdd(&gacc[g0], p * 0.25f);
    } else {
        if (valid && q == 0) unsafeAtomicAdd(&gacc[g], p);
    }

    if (!last && valid && q == 0) {
        float yn[10];
#pragma unroll
        for (int j = 0; j < 10; j++) {
            float v = 0.f;
#pragma unroll
            for (int k = 0; k < 10; k++) v += x[k] * sW1[k * 10 + j];
            yn[j] = v;
        }
        unsigned r0 = (unsigned)f2bf(yn[0]) | ((unsigned)f2bf(yn[1]) << 16);
        unsigned r1 = (unsigned)f2bf(yn[2]) | ((unsigned)f2bf(yn[3]) << 16);
        unsigned r2 = (unsigned)f2bf(yn[4]) | ((unsigned)f2bf(yn[5]) << 16);
        unsigned r3 = (unsigned)f2bf(yn[6]) | ((unsigned)f2bf(yn[7]) << 16);
        unsigned r4 = (unsigned)f2bf(yn[8]) | ((unsigned)f2bf(yn[9]) << 16);
        unsigned* yo = yout + (size_t)n * 8;
        *(uint4*)yo = make_uint4(r0, r1, r2, r3);
        yo[4] = r4;
    }
}

// ---------------- Final: out[g] = sigmoid(gacc[g] / max(count,1)) ----------------
__global__ void k4_final(const float* __restrict__ gacc, const int* __restrict__ node_graph,
                         float* __restrict__ out, int N, int G) {
    int g = blockIdx.x * blockDim.x + threadIdx.x;
    if (g >= G) return;
    int lo = 0, hi = N;
    while (lo < hi) { int m = (lo + hi) >> 1; if (node_graph[m] < g) lo = m + 1; else hi = m; }
    int lo2 = lo, hi2 = N;
    while (lo2 < hi2) { int m = (lo2 + hi2) >> 1; if (node_graph[m] <= g) lo2 = m + 1; else hi2 = m; }
    float c = (float)(hi2 - lo);
    if (c < 1.f) c = 1.f;
    float s = gacc[g] / c;
    out[g] = 1.f / (1.f + __expf(-s));
}

// ============ R4 fallback fused layer (f32 rows, src-only edges) ============
__global__ __launch_bounds__(256) void k_layer(
        const float* __restrict__ yin, float* __restrict__ yout,
        const unsigned* __restrict__ row_start, const unsigned* __restrict__ edges,
        const float* __restrict__ b1, const float* __restrict__ W2,
        const float* __restrict__ b2, const float* __restrict__ l,
        const float* __restrict__ W1n,
        const int* __restrict__ node_graph, float* __restrict__ gacc,
        int N, int last) {
    __shared__ float sW2[100], sW1[100], sb1[10], sb2[10], sl[10];
    int t = threadIdx.x;
    if (t < 100) sW2[t] = W2[t];
    if (!last && t >= 128 && t < 228) sW1[t - 128] = W1n[t - 128];
    if (t < 10) { sb1[t] = b1[t]; sb2[t] = b2[t]; sl[t] = l[t]; }
    __syncthreads();
    int n = blockIdx.x * 256 + t;
    bool valid = n < N;
    int nc = valid ? n : (N - 1);
    const float* yr = yin + (size_t)nc * 16;
    float4 a = *(const float4*)yr;
    float4 b = *(const float4*)(yr + 4);
    float2 c = *(const float2*)(yr + 8);
    float acc[10] = {a.x, a.y, a.z, a.w, b.x, b.y, b.z, b.w, c.x, c.y};
    unsigned beg = 0, end = 0;
    if (valid) { beg = row_start[n]; end = row_start[n + 1]; }
    for (unsigned e = beg; e < end; ++e) {
        unsigned s = edges[e];
        const float* pr = yin + (size_t)s * 16;
        float4 pa = *(const float4*)pr;
        float4 pb = *(const float4*)(pr + 4);
        float2 pc = *(const float2*)(pr + 8);
        acc[0] += pa.x; acc[1] += pa.y; acc[2] += pa.z; acc[3] += pa.w;
        acc[4] += pb.x; acc[5] += pb.y; acc[6] += pb.z; acc[7] += pb.w;
        acc[8] += pc.x; acc[9] += pc.y;
    }
    float z[10], x[10];
#pragma unroll
    for (int j = 0; j < 10; j++) {
        float v = acc[j] + sb1[j];
        z[j] = v > 0.f ? v : 0.f;
    }
#pragma unroll
    for (int j = 0; j < 10; j++) {
        float v = sb2[j];
#pragma unroll
        for (int k = 0; k < 10; k++) v += z[k] * sW2[k * 10 + j];
        x[j] = v > 0.f ? v : 0.f;
    }
    float p = 0.f;
#pragma unroll
    for (int j = 0; j < 10; j++) p += x[j] * sl[j];
    if (!valid) p = 0.f;
    int g = node_graph[nc];
    int g0 = __shfl(g, 0);
    if (__all(g == g0)) {
#pragma unroll
        for (int off = 32; off > 0; off >>= 1) p += __shfl_down(p, off);
        if ((t & 63) == 0) unsafeAtomicAdd(&gacc[g0], p);
    } else {
        if (valid) unsafeAtomicAdd(&gacc[g], p);
    }
    if (!last && valid) {
        float yn[10];
#pragma unroll
        for (int j = 0; j < 10; j++) {
            float v = 0.f;
#pragma unroll
            for (int k = 0; k < 10; k++) v += x[k] * sW1[k * 10 + j];
            yn[j] = v;
        }
        float* yo = yout + (size_t)n * 16;
        *(float4*)yo = make_float4(yn[0], yn[1], yn[2], yn[3]);
        *(float4*)(yo + 4) = make_float4(yn[4], yn[5], yn[6], yn[7]);
        *(float2*)(yo + 8) = make_float2(yn[8], yn[9]);
    }
}

static inline size_t al16(size_t w) { return (w + 15) & ~(size_t)15; }

extern "C" void kernel_launch(void* const* d_in, const int* in_sizes, int n_in,
                              void* d_out, int out_size, void* d_ws, size_t ws_size,
                              hipStream_t stream) {
    const float* h  = (const float*)d_in[0];
    const int* src  = (const int*)d_in[1];
    const int* dst  = (const int*)d_in[2];
    const int* ng   = (const int*)d_in[3];
    int N = in_sizes[3];
    int E = in_sizes[1];
    int G = out_size;

    const float* W1[5]; const float* b1[5]; const float* W2[5]; const float* b2[5]; const float* l[5];
    for (int i = 0; i < 5; i++) {
        W1[i] = (const float*)d_in[4 + i * 5 + 0];
        b1[i] = (const float*)d_in[4 + i * 5 + 1];
        W2[i] = (const float*)d_in[4 + i * 5 + 2];
        b2[i] = (const float*)d_in[4 + i * 5 + 3];
        l[i]  = (const float*)d_in[4 + i * 5 + 4];
    }
    float* out = (float*)d_out;

    int nbScan = (N + 8191) / 8192;   // scan blocks (8192 elems each)

    // R14 layout (4B words): y0[N*8] | y1[N*8] | edges[E] | row_start[N+1]
    //   | cnt[N] | cur[N] | bsum[1024] | gacc[G]
    size_t wY   = al16((size_t)N * 8);
    size_t wE   = al16((size_t)E);
    size_t wRS  = al16((size_t)N + 1);
    size_t wN   = al16((size_t)N);
    size_t need_r14 = (2 * wY + wE + wRS + 2 * wN + 1024 + al16((size_t)G)) * 4;

    size_t regY = (size_t)N * 16;
    size_t need_r4 = (2 * regY + (size_t)E + (size_t)(N + 1) + 2 * wN + 1024 +
                      (size_t)G) * 4;

    if (ws_size >= need_r14 && nbScan <= 1024) {
        unsigned* y0 = (unsigned*)d_ws;
        unsigned* y1 = y0 + wY;
        unsigned* edges = y1 + wY;
        unsigned* row_start = edges + wE;
        unsigned* cnt = row_start + wRS;
        unsigned* cur = cnt + wN;
        unsigned* bsum = cur + wN;
        float* gacc = (float*)(bsum + 1024);

        hipMemsetAsync(cnt, 0, (size_t)N * 4, stream);
        hipMemsetAsync(gacc, 0, (size_t)G * 4, stream);

        k1_hw1_bf16<<<(N + 255) / 256, 256, 0, stream>>>(h, W1[0], y0, N);

        k_histN<<<2048, 256, 0, stream>>>(dst, cnt, E);
        k_scanA<<<nbScan, 1024, 0, stream>>>(cnt, bsum, N);
        k_scanB<<<1, 1024, 0, stream>>>(bsum, nbScan);
        k_scanC<<<nbScan, 1024, 0, stream>>>(cnt, bsum, row_start, cur, N, E);
        k_scatterN<<<2048, 256, 0, stream>>>(src, dst, cur, edges, E);

        unsigned* ybuf[2] = {y0, y1};
        int qblocks = (N + 63) / 64;
        for (int i = 0; i < 5; i++) {
            k_layerQ<<<qblocks, 256, 0, stream>>>(
                ybuf[i & 1], ybuf[(i + 1) & 1], row_start, edges,
                b1[i], W2[i], b2[i], l[i], i < 4 ? W1[i + 1] : nullptr,
                ng, gacc, N, i == 4 ? 1 : 0);
        }
        k4_final<<<(G + 255) / 256, 256, 0, stream>>>(gacc, ng, out, N, G);
        return;
    }

    // fallback: R4 path (f32 rows, fused node-parallel layer over full CSR)
    if (ws_size >= need_r4 && nbScan <= 1024) {
        float* y0 = (float*)d_ws;
        float* y1 = y0 + regY;
        unsigned* edges = (unsigned*)(y1 + regY);
        unsigned* row_start = edges + E;
        unsigned* cnt = row_start + (N + 1);
        unsigned* cur = cnt + wN;
        unsigned* bsum = cur + wN;
        float* gacc = (float*)(bsum + 1024);

        hipMemsetAsync(cnt, 0, (size_t)N * 4, stream);
        hipMemsetAsync(gacc, 0, (size_t)G * 4, stream);

        k1_hw1_f32<<<(N + 255) / 256, 256, 0, stream>>>(h, W1[0], y0, N);
        k_histN<<<2048, 256, 0, stream>>>(dst, cnt, E);
        k_scanA<<<nbScan, 1024, 0, stream>>>(cnt, bsum, N);
        k_scanB<<<1, 1024, 0, stream>>>(bsum, nbScan);
        k_scanC<<<nbScan, 1024, 0, stream>>>(cnt, bsum, row_start, cur, N, E);
        k_scatterN<<<2048, 256, 0, stream>>>(src, dst, cur, edges, E);

        float* ybuf[2] = {y0, y1};
        for (int i = 0; i < 5; i++) {
            k_layer<<<(N + 255) / 256, 256, 0, stream>>>(
                ybuf[i & 1], ybuf[(i + 1) & 1], row_start, edges,
                b1[i], W2[i], b2[i], l[i], i < 4 ? W1[i + 1] : nullptr,
                ng, gacc, N, i == 4 ? 1 : 0);
        }
        k4_final<<<(G + 255) / 256, 256, 0, stream>>>(gacc, ng, out, N, G);
    }
}

// Round 8
// 1979.617 us; speedup vs baseline: 1.6417x; 1.6417x over previous
//
#include <hip/hip_runtime.h>

// GIN: 5 layers, DIM=10. Identity: (x+agg)@W1 = x@W1 + segsum((x@W1)[src]).
// R15 = R13 (best verified, 1994us): bucketed CSR build + quad-per-node hot
// phase at 64 VGPR / no spill. Reverts R14's global-atomic build experiment.
// Measured ladder of failure modes now brackets the design:
//  - R8: LDS atomics ~3.3 cy/lane-op (per-CU, occupancy-insensitive) ->
//    never >=1 per edge-feature on hot path (899us/layer).
//  - R14: random 4B global writes/atomics across 64MB -> full-line RMW +
//    cross-XCD atomic round-trips, 733 GB/s, 1450us for ONE scatter pass.
//    Bucketed two-phase (L2-resident 128KB windows) is the right structure.
//  - R11/R12: launch_bounds(256,8) => hipcc caps VGPR at 32 (its budget model
//    is 256/EU) and spills 1.4GB/layer; (256,4) => cap 64, no spill.
//  - Hot phase: kA(scan,82%occ), R10(quad,32%), R13(quad,42%) all converge to
//    3.5-3.8 TB/s on the random 32B-row gather stream (ceiling ~4.3, R11) ->
//    pattern-bound, further issue-tuning is low-value.

#define NBLK 256   // scatter blocks (must match k_cnt/k_scatter grids)

__device__ __forceinline__ unsigned short f2bf(float f) {
    unsigned b = __float_as_uint(f);
    b += 0x7fffu + ((b >> 16) & 1u);   // round-to-nearest-even
    return (unsigned short)(b >> 16);
}
__device__ __forceinline__ float bflo(unsigned u) { return __uint_as_float(u << 16); }
__device__ __forceinline__ float bfhi(unsigned u) { return __uint_as_float(u & 0xffff0000u); }

// ---------------- Layer-1: y = h @ W1_1 (bf16 rows, 8 uints/row) ----------------
__global__ void k1_hw1_bf16(const float* __restrict__ h, const float* __restrict__ W1,
                            unsigned* __restrict__ y, int N) {
    __shared__ float sW[640];
    for (int i = threadIdx.x; i < 640; i += blockDim.x) sW[i] = W1[i];
    __syncthreads();
    int n = blockIdx.x * blockDim.x + threadIdx.x;
    if (n >= N) return;
    const float* hr = h + (size_t)n * 64;
    float acc[10];
#pragma unroll
    for (int j = 0; j < 10; j++) acc[j] = 0.f;
#pragma unroll 4
    for (int k = 0; k < 64; k += 4) {
        float4 hv = *(const float4*)(hr + k);
#pragma unroll
        for (int j = 0; j < 10; j++) {
            acc[j] += hv.x * sW[(k + 0) * 10 + j];
            acc[j] += hv.y * sW[(k + 1) * 10 + j];
            acc[j] += hv.z * sW[(k + 2) * 10 + j];
            acc[j] += hv.w * sW[(k + 3) * 10 + j];
        }
    }
    unsigned r0 = (unsigned)f2bf(acc[0]) | ((unsigned)f2bf(acc[1]) << 16);
    unsigned r1 = (unsigned)f2bf(acc[2]) | ((unsigned)f2bf(acc[3]) << 16);
    unsigned r2 = (unsigned)f2bf(acc[4]) | ((unsigned)f2bf(acc[5]) << 16);
    unsigned r3 = (unsigned)f2bf(acc[6]) | ((unsigned)f2bf(acc[7]) << 16);
    unsigned r4 = (unsigned)f2bf(acc[8]) | ((unsigned)f2bf(acc[9]) << 16);
    unsigned* yr = y + (size_t)n * 8;
    *(uint4*)yr = make_uint4(r0, r1, r2, r3);
    yr[4] = r4;
}

// f32 variant for the fallback path (16-float rows)
__global__ void k1_hw1_f32(const float* __restrict__ h, const float* __restrict__ W1,
                           float* __restrict__ y, int N) {
    __shared__ float sW[640];
    for (int i = threadIdx.x; i < 640; i += blockDim.x) sW[i] = W1[i];
    __syncthreads();
    int n = blockIdx.x * blockDim.x + threadIdx.x;
    if (n >= N) return;
    const float* hr = h + (size_t)n * 64;
    float acc[10];
#pragma unroll
    for (int j = 0; j < 10; j++) acc[j] = 0.f;
#pragma unroll 4
    for (int k = 0; k < 64; k += 4) {
        float4 hv = *(const float4*)(hr + k);
#pragma unroll
        for (int j = 0; j < 10; j++) {
            acc[j] += hv.x * sW[(k + 0) * 10 + j];
            acc[j] += hv.y * sW[(k + 1) * 10 + j];
            acc[j] += hv.z * sW[(k + 2) * 10 + j];
            acc[j] += hv.w * sW[(k + 3) * 10 + j];
        }
    }
    float* yr = y + (size_t)n * 16;
#pragma unroll
    for (int j = 0; j < 10; j++) yr[j] = acc[j];
}

// =================== CSR build v2: count -> scan -> scatter ===================
__global__ __launch_bounds__(1024) void k_cnt(
        const int* __restrict__ dst, unsigned* __restrict__ gcnt, int E) {
    __shared__ unsigned h[512];
    int t = threadIdx.x;
    if (t < 512) h[t] = 0;
    __syncthreads();
    int per = (E + NBLK - 1) / NBLK;
    int beg = blockIdx.x * per;
    int end = beg + per; if (end > E) end = E;
    for (int e = beg + t; e < end; e += 1024)
        atomicAdd(&h[(unsigned)dst[e] >> 10], 1u);
    __syncthreads();
    if (t < 512) gcnt[blockIdx.x * 512 + t] = h[t];
}

__global__ __launch_bounds__(NBLK) void k_scan2(
        const unsigned* __restrict__ gcnt, unsigned* __restrict__ gbase,
        unsigned* __restrict__ btot) {
    __shared__ unsigned s[NBLK];
    int b = blockIdx.x;          // bucket
    int t = threadIdx.x;         // scatter-block index
    unsigned v = gcnt[t * 512 + b];
    s[t] = v;
    __syncthreads();
    for (int off = 1; off < NBLK; off <<= 1) {
        unsigned u = (t >= off) ? s[t - off] : 0u;
        __syncthreads();
        s[t] += u;
        __syncthreads();
    }
    gbase[t * 512 + b] = s[t] - v;           // exclusive
    if (t == NBLK - 1) btot[b] = s[t];
}

__global__ void k_bscan(const unsigned* __restrict__ btot,
                        unsigned* __restrict__ bbase, int B) {
    __shared__ unsigned s[512];
    int t = threadIdx.x;
    unsigned v = (t < B) ? btot[t] : 0u;
    s[t] = v;
    __syncthreads();
    for (int off = 1; off < 512; off <<= 1) {
        unsigned u = (t >= off) ? s[t - off] : 0u;
        __syncthreads();
        s[t] += u;
        __syncthreads();
    }
    if (t < B) bbase[t] = s[t] - v;
    if (t == B - 1) bbase[B] = s[t];
}

__global__ __launch_bounds__(1024) void k_scatter(
        const int* __restrict__ src, const int* __restrict__ dst,
        const unsigned* __restrict__ bbase, const unsigned* __restrict__ gbase,
        unsigned* __restrict__ pairs, int E) {
    __shared__ unsigned cur[512];
    int t = threadIdx.x;
    if (t < 512) cur[t] = bbase[t] + gbase[blockIdx.x * 512 + t];
    __syncthreads();
    int per = (E + NBLK - 1) / NBLK;
    int beg = blockIdx.x * per;
    int end = beg + per; if (end > E) end = E;
    for (int e = beg + t; e < end; e += 1024) {
        unsigned d = (unsigned)dst[e];
        unsigned pos = atomicAdd(&cur[d >> 10], 1u);
        pairs[pos] = ((unsigned)src[e] << 10) | (d & 1023u);
    }
}

// k_p2: per-bucket node sort -> edges (src-only when packed=0) + row_start CSR
__global__ __launch_bounds__(1024) void k_p2(
        const unsigned* __restrict__ pairs, const unsigned* __restrict__ bbase,
        unsigned* __restrict__ edges, unsigned* __restrict__ row_start,
        int N, int B, int E, int packed) {
    __shared__ unsigned cnt[1024], scn[1024], cur[1024];
    int t = threadIdx.x, b = blockIdx.x;
    unsigned beg = bbase[b], end = bbase[b + 1];
    cnt[t] = 0;
    __syncthreads();
    for (unsigned e = beg + t; e < end; e += 1024)
        atomicAdd(&cnt[pairs[e] & 1023u], 1u);
    __syncthreads();
    unsigned v = cnt[t];
    scn[t] = v;
    __syncthreads();
    for (int off = 1; off < 1024; off <<= 1) {
        unsigned u = (t >= off) ? scn[t - off] : 0u;
        __syncthreads();
        scn[t] += u;
        __syncthreads();
    }
    unsigned excl = scn[t] - v;
    int node = (b << 10) + t;
    if (node < N) row_start[node] = beg + excl;
    if (b == B - 1 && t == 0) row_start[N] = (unsigned)E;
    cur[t] = beg + excl;
    __syncthreads();
    for (unsigned e = beg + t; e < end; e += 1024) {
        unsigned pv = pairs[e];
        unsigned pos = atomicAdd(&cur[pv & 1023u], 1u);
        edges[pos] = packed ? pv : (pv >> 10);
    }
}

// =================== hot phase: quad-per-node fused layer (bf16 rows) ===================
// 4 lanes per node, stride-4 single-row loop with next-edge-index prefetch,
// 20 shfl_xor combine, redundant MLP in all 4 lanes, q==0 writes y_next.
// launch_bounds(256,4): hipcc caps VGPR at 64 -> no spill (R11/R12 lesson).
__global__ __launch_bounds__(256, 4) void k_layerQ(
        const unsigned* __restrict__ yin, unsigned* __restrict__ yout,
        const unsigned* __restrict__ row_start, const unsigned* __restrict__ edges,
        const float* __restrict__ b1, const float* __restrict__ W2,
        const float* __restrict__ b2, const float* __restrict__ l,
        const float* __restrict__ W1n,
        const int* __restrict__ node_graph, float* __restrict__ gacc,
        int N, int last) {
    __shared__ float sW2[100], sW1[100], sb1[10], sb2[10], sl[10];
    int t = threadIdx.x;
    if (t < 100) sW2[t] = W2[t];
    if (!last && t >= 128 && t < 228) sW1[t - 128] = W1n[t - 128];
    if (t < 10) { sb1[t] = b1[t]; sb2[t] = b2[t]; sl[t] = l[t]; }
    __syncthreads();
    int q = t & 3;
    int n = blockIdx.x * 64 + (t >> 2);
    bool valid = n < N;
    int nc = valid ? n : (N - 1);

    float acc[10];
#pragma unroll
    for (int j = 0; j < 10; j++) acc[j] = 0.f;

    unsigned beg = 0, end = 0;
    if (valid) { beg = row_start[n]; end = row_start[n + 1]; }
    unsigned e = beg + (unsigned)q;
    bool have = e < end;
    unsigned sNext = 0;
    if (have) sNext = edges[e];
    while (have) {
        unsigned sCur = sNext;
        unsigned en = e + 4;
        bool hn = en < end;
        if (hn) sNext = edges[en];           // prefetch next edge index
        const unsigned* p = yin + (size_t)sCur * 8;
        uint4 a0 = *(const uint4*)p;
        unsigned b0 = p[4];
        acc[0] += bflo(a0.x); acc[1] += bfhi(a0.x);
        acc[2] += bflo(a0.y); acc[3] += bfhi(a0.y);
        acc[4] += bflo(a0.z); acc[5] += bfhi(a0.z);
        acc[6] += bflo(a0.w); acc[7] += bfhi(a0.w);
        acc[8] += bflo(b0);   acc[9] += bfhi(b0);
        e = en; have = hn;
    }

#pragma unroll
    for (int j = 0; j < 10; j++) acc[j] += __shfl_xor(acc[j], 1);
#pragma unroll
    for (int j = 0; j < 10; j++) acc[j] += __shfl_xor(acc[j], 2);

    const unsigned* yr = yin + (size_t)nc * 8;
    uint4 qa = *(const uint4*)yr;
    unsigned q4 = yr[4];
    acc[0] += bflo(qa.x); acc[1] += bfhi(qa.x);
    acc[2] += bflo(qa.y); acc[3] += bfhi(qa.y);
    acc[4] += bflo(qa.z); acc[5] += bfhi(qa.z);
    acc[6] += bflo(qa.w); acc[7] += bfhi(qa.w);
    acc[8] += bflo(q4);   acc[9] += bfhi(q4);

    float z[10], x[10];
#pragma unroll
    for (int j = 0; j < 10; j++) {
        float v = acc[j] + sb1[j];
        z[j] = v > 0.f ? v : 0.f;
    }
#pragma unroll
    for (int j = 0; j < 10; j++) {
        float v = sb2[j];
#pragma unroll
        for (int k = 0; k < 10; k++) v += z[k] * sW2[k * 10 + j];
        x[j] = v > 0.f ? v : 0.f;
    }
    float p = 0.f;
#pragma unroll
    for (int j = 0; j < 10; j++) p += x[j] * sl[j];
    if (!valid) p = 0.f;
    int g = node_graph[nc];

    int g0 = __shfl(g, 0);
    if (__all(g == g0)) {
        // every node's p appears in 4 lanes -> wave sum is 4x the true sum
#pragma unroll
        for (int off = 32; off > 0; off >>= 1) p += __shfl_down(p, off);
        if ((t & 63) == 0) unsafeAtomicAdd(&gacc[g0], p * 0.25f);
    } else {
        if (valid && q == 0) unsafeAtomicAdd(&gacc[g], p);
    }

    if (!last && valid && q == 0) {
        float yn[10];
#pragma unroll
        for (int j = 0; j < 10; j++) {
            float v = 0.f;
#pragma unroll
            for (int k = 0; k < 10; k++) v += x[k] * sW1[k * 10 + j];
            yn[j] = v;
        }
        unsigned r0 = (unsigned)f2bf(yn[0]) | ((unsigned)f2bf(yn[1]) << 16);
        unsigned r1 = (unsigned)f2bf(yn[2]) | ((unsigned)f2bf(yn[3]) << 16);
        unsigned r2 = (unsigned)f2bf(yn[4]) | ((unsigned)f2bf(yn[5]) << 16);
        unsigned r3 = (unsigned)f2bf(yn[6]) | ((unsigned)f2bf(yn[7]) << 16);
        unsigned r4 = (unsigned)f2bf(yn[8]) | ((unsigned)f2bf(yn[9]) << 16);
        unsigned* yo = yout + (size_t)n * 8;
        *(uint4*)yo = make_uint4(r0, r1, r2, r3);
        yo[4] = r4;
    }
}

// ---------------- Final: out[g] = sigmoid(gacc[g] / max(count,1)) ----------------
__global__ void k4_final(const float* __restrict__ gacc, const int* __restrict__ node_graph,
                         float* __restrict__ out, int N, int G) {
    int g = blockIdx.x * blockDim.x + threadIdx.x;
    if (g >= G) return;
    int lo = 0, hi = N;
    while (lo < hi) { int m = (lo + hi) >> 1; if (node_graph[m] < g) lo = m + 1; else hi = m; }
    int lo2 = lo, hi2 = N;
    while (lo2 < hi2) { int m = (lo2 + hi2) >> 1; if (node_graph[m] <= g) lo2 = m + 1; else hi2 = m; }
    float c = (float)(hi2 - lo);
    if (c < 1.f) c = 1.f;
    float s = gacc[g] / c;
    out[g] = 1.f / (1.f + __expf(-s));
}

// ============ R4 fallback fused layer (f32 rows, src-only edges) ============
__global__ __launch_bounds__(256) void k_layer(
        const float* __restrict__ yin, float* __restrict__ yout,
        const unsigned* __restrict__ row_start, const unsigned* __restrict__ edges,
        const float* __restrict__ b1, const float* __restrict__ W2,
        const float* __restrict__ b2, const float* __restrict__ l,
        const float* __restrict__ W1n,
        const int* __restrict__ node_graph, float* __restrict__ gacc,
        int N, int last) {
    __shared__ float sW2[100], sW1[100], sb1[10], sb2[10], sl[10];
    int t = threadIdx.x;
    if (t < 100) sW2[t] = W2[t];
    if (!last && t >= 128 && t < 228) sW1[t - 128] = W1n[t - 128];
    if (t < 10) { sb1[t] = b1[t]; sb2[t] = b2[t]; sl[t] = l[t]; }
    __syncthreads();
    int n = blockIdx.x * 256 + t;
    bool valid = n < N;
    int nc = valid ? n : (N - 1);
    const float* yr = yin + (size_t)nc * 16;
    float4 a = *(const float4*)yr;
    float4 b = *(const float4*)(yr + 4);
    float2 c = *(const float2*)(yr + 8);
    float acc[10] = {a.x, a.y, a.z, a.w, b.x, b.y, b.z, b.w, c.x, c.y};
    unsigned beg = 0, end = 0;
    if (valid) { beg = row_start[n]; end = row_start[n + 1]; }
    for (unsigned e = beg; e < end; ++e) {
        unsigned s = edges[e];
        const float* pr = yin + (size_t)s * 16;
        float4 pa = *(const float4*)pr;
        float4 pb = *(const float4*)(pr + 4);
        float2 pc = *(const float2*)(pr + 8);
        acc[0] += pa.x; acc[1] += pa.y; acc[2] += pa.z; acc[3] += pa.w;
        acc[4] += pb.x; acc[5] += pb.y; acc[6] += pb.z; acc[7] += pb.w;
        acc[8] += pc.x; acc[9] += pc.y;
    }
    float z[10], x[10];
#pragma unroll
    for (int j = 0; j < 10; j++) {
        float v = acc[j] + sb1[j];
        z[j] = v > 0.f ? v : 0.f;
    }
#pragma unroll
    for (int j = 0; j < 10; j++) {
        float v = sb2[j];
#pragma unroll
        for (int k = 0; k < 10; k++) v += z[k] * sW2[k * 10 + j];
        x[j] = v > 0.f ? v : 0.f;
    }
    float p = 0.f;
#pragma unroll
    for (int j = 0; j < 10; j++) p += x[j] * sl[j];
    if (!valid) p = 0.f;
    int g = node_graph[nc];
    int g0 = __shfl(g, 0);
    if (__all(g == g0)) {
#pragma unroll
        for (int off = 32; off > 0; off >>= 1) p += __shfl_down(p, off);
        if ((t & 63) == 0) unsafeAtomicAdd(&gacc[g0], p);
    } else {
        if (valid) unsafeAtomicAdd(&gacc[g], p);
    }
    if (!last && valid) {
        float yn[10];
#pragma unroll
        for (int j = 0; j < 10; j++) {
            float v = 0.f;
#pragma unroll
            for (int k = 0; k < 10; k++) v += x[k] * sW1[k * 10 + j];
            yn[j] = v;
        }
        float* yo = yout + (size_t)n * 16;
        *(float4*)yo = make_float4(yn[0], yn[1], yn[2], yn[3]);
        *(float4*)(yo + 4) = make_float4(yn[4], yn[5], yn[6], yn[7]);
        *(float2*)(yo + 8) = make_float2(yn[8], yn[9]);
    }
}

static inline size_t al16(size_t w) { return (w + 15) & ~(size_t)15; }

extern "C" void kernel_launch(void* const* d_in, const int* in_sizes, int n_in,
                              void* d_out, int out_size, void* d_ws, size_t ws_size,
                              hipStream_t stream) {
    const float* h  = (const float*)d_in[0];
    const int* src  = (const int*)d_in[1];
    const int* dst  = (const int*)d_in[2];
    const int* ng   = (const int*)d_in[3];
    int N = in_sizes[3];
    int E = in_sizes[1];
    int G = out_size;

    const float* W1[5]; const float* b1[5]; const float* W2[5]; const float* b2[5]; const float* l[5];
    for (int i = 0; i < 5; i++) {
        W1[i] = (const float*)d_in[4 + i * 5 + 0];
        b1[i] = (const float*)d_in[4 + i * 5 + 1];
        W2[i] = (const float*)d_in[4 + i * 5 + 2];
        b2[i] = (const float*)d_in[4 + i * 5 + 3];
        l[i]  = (const float*)d_in[4 + i * 5 + 4];
    }
    float* out = (float*)d_out;

    int B = (N + 1023) >> 10;

    // R15 layout (4B words): y0[N*8] | reg2 = max(pairs[E], y1[N*8]) | edges[E]
    //   | row_start[N+1] | btot[512] | bbase[513->528] | gcnt[NBLK*512]
    //   | gbase[NBLK*512] | gacc[G]
    size_t wY   = al16((size_t)N * 8);
    size_t wRg2 = al16(((size_t)E > (size_t)N * 8) ? (size_t)E : (size_t)N * 8);
    size_t wE   = al16((size_t)E);
    size_t wRS  = al16((size_t)N + 1);
    size_t wGrid = (size_t)NBLK * 512;
    size_t need_r15 = (wY + wRg2 + wE + wRS + 1040 + 2 * wGrid + al16((size_t)G)) * 4;

    size_t regAB = (size_t)N * 16;
    size_t reg2f = ((size_t)E > regAB) ? (size_t)E : regAB;
    size_t need_r4 = (regAB + reg2f + (size_t)E + (size_t)(N + 1) + 1040 +
                      2 * wGrid + (size_t)G) * 4;

    if (ws_size >= need_r15 && B <= 512) {
        unsigned* y0 = (unsigned*)d_ws;
        unsigned* pairs = y0 + wY;
        unsigned* y1 = pairs;              // pairs dead after k_p2
        unsigned* edges = pairs + wRg2;
        unsigned* row_start = edges + wE;
        unsigned* btot = row_start + wRS;
        unsigned* bbase = btot + 512;
        unsigned* gcnt = bbase + 528;      // 513 used, pad to 16
        unsigned* gbase = gcnt + wGrid;
        float* gacc = (float*)(gbase + wGrid);

        hipMemsetAsync(gacc, 0, (size_t)G * 4, stream);

        k1_hw1_bf16<<<(N + 255) / 256, 256, 0, stream>>>(h, W1[0], y0, N);

        k_cnt<<<NBLK, 1024, 0, stream>>>(dst, gcnt, E);
        k_scan2<<<512, NBLK, 0, stream>>>(gcnt, gbase, btot);
        k_bscan<<<1, 512, 0, stream>>>(btot, bbase, B);
        k_scatter<<<NBLK, 1024, 0, stream>>>(src, dst, bbase, gbase, pairs, E);
        k_p2<<<B, 1024, 0, stream>>>(pairs, bbase, edges, row_start, N, B, E, 0);

        unsigned* ybuf[2] = {y0, y1};
        int qblocks = (N + 63) / 64;
        for (int i = 0; i < 5; i++) {
            k_layerQ<<<qblocks, 256, 0, stream>>>(
                ybuf[i & 1], ybuf[(i + 1) & 1], row_start, edges,
                b1[i], W2[i], b2[i], l[i], i < 4 ? W1[i + 1] : nullptr,
                ng, gacc, N, i == 4 ? 1 : 0);
        }
        k4_final<<<(G + 255) / 256, 256, 0, stream>>>(gacc, ng, out, N, G);
        return;
    }

    // fallback: R4 path (f32 rows, fused node-parallel layer over full CSR)
    if (ws_size >= need_r4 && B <= 512) {
        float* y0 = (float*)d_ws;
        unsigned* pairs = (unsigned*)(y0 + regAB);
        float* y1 = (float*)pairs;
        unsigned* edges = pairs + reg2f;
        unsigned* row_start = edges + E;
        unsigned* btot = row_start + (N + 1);
        unsigned* bbase = btot + 512;
        unsigned* gcnt = bbase + 528;
        unsigned* gbase = gcnt + wGrid;
        float* gacc = (float*)(gbase + wGrid);

        hipMemsetAsync(gacc, 0, (size_t)G * 4, stream);

        k1_hw1_f32<<<(N + 255) / 256, 256, 0, stream>>>(h, W1[0], y0, N);
        k_cnt<<<NBLK, 1024, 0, stream>>>(dst, gcnt, E);
        k_scan2<<<512, NBLK, 0, stream>>>(gcnt, gbase, btot);
        k_bscan<<<1, 512, 0, stream>>>(btot, bbase, B);
        k_scatter<<<NBLK, 1024, 0, stream>>>(src, dst, bbase, gbase, pairs, E);
        k_p2<<<B, 1024, 0, stream>>>(pairs, bbase, edges, row_start, N, B, E, 0);

        float* ybuf[2] = {y0, y1};
        for (int i = 0; i < 5; i++) {
            k_layer<<<(N + 255) / 256, 256, 0, stream>>>(
                ybuf[i & 1], ybuf[(i + 1) & 1], row_start, edges,
                b1[i], W2[i], b2[i], l[i], i < 4 ? W1[i + 1] : nullptr,
                ng, gacc, N, i == 4 ? 1 : 0);
        }
        k4_final<<<(G + 255) / 256, 256, 0, stream>>>(gacc, ng, out, N, G);
    }
}